// Round 1
// baseline (4029.802 us; speedup 1.0000x reference)
//
#include <hip/hip_runtime.h>
#include <hip/hip_bf16.h>

// Problem constants
#define NB 8       // batch
#define NH 16      // heads
#define NBH 128    // NB*NH
#define LS 1024    // sequence length
#define DD 64      // head dim
#define DM 1024    // d_model = NH*DD
#define QT 16      // q rows per attn block
#define KT 256     // k rows staged per super-iteration
#define SCALEF 0.125f  // 1/sqrt(64)

// ---------------------------------------------------------------------------
// Gate kernel: gate[b,h,k] = sigmoid(W2 . tanh(W1 @ pt[b,h,k] + b1) + b2)
// One wave per row; block = 256 threads = 4 rows.
// ---------------------------------------------------------------------------
__global__ __launch_bounds__(256) void gate_kernel(
    const float* __restrict__ pt, const float* __restrict__ W1,
    const float* __restrict__ b1, const float* __restrict__ W2,
    const float* __restrict__ b2, float* __restrict__ gate)
{
    int row  = blockIdx.x * 4 + (threadIdx.x >> 6);   // < NBH*LS
    int lane = threadIdx.x & 63;
    const float* x = pt + (size_t)row * DD;
    float xv = x[lane];                                // lane d holds x[d]
    // h_e for e = lane
    float acc = b1[lane];
    const float* w1r = W1 + lane * DD;                 // W1[e][d], row e
    #pragma unroll 16
    for (int d = 0; d < DD; ++d)
        acc += w1r[d] * __shfl(xv, d);
    float h = tanhf(acc);
    float r = W2[lane] * h;
    #pragma unroll
    for (int off = 32; off > 0; off >>= 1)
        r += __shfl_down(r, off);
    if (lane == 0)
        gate[row] = 1.0f / (1.0f + expf(-(r + b2[0])));
}

// ---------------------------------------------------------------------------
// Fused attention: scores (fp32, LDS) -> softmax -> *gate -> weights (global)
//                  -> PV -> tmp (bf16, ws)
// Block: 256 threads (4 waves), one (bh, 16-q-row tile).
// LDS: sS 16x1028 f32 (64.25KB) + sQ 16x68 (4.25KB) + sKV 256x68 (68KB)
//      = 136.5 KB (gfx950: 160 KB/WG available) -> 1 block/CU.
// ---------------------------------------------------------------------------
__global__ __launch_bounds__(256) void attn_kernel(
    const float* __restrict__ Q, const float* __restrict__ Kmat,
    const float* __restrict__ V, const float* __restrict__ bias,
    const float* __restrict__ gate, float* __restrict__ Wout,
    __hip_bfloat16* __restrict__ tmp)
{
    __shared__ __align__(16) float sS[QT][LS + 4];    // scores, pad +4
    __shared__ __align__(16) float sQ[QT][DD + 4];    // q tile (pre-scaled)
    __shared__ __align__(16) float sKV[KT][DD + 4];   // K/V staging

    const int bh = blockIdx.y;
    const int q0 = blockIdx.x * QT;
    const int t  = threadIdx.x;
    const int w  = t >> 6;           // wave id 0..3
    const int l  = t & 63;           // lane
    const size_t hoff = (size_t)bh * LS * DD;

    // ---- stage Q tile (scaled) ----
    {
        const float4* g = (const float4*)(Q + hoff + (size_t)q0 * DD);
        for (int i = t; i < QT * 16; i += 256) {
            int r = i >> 4, c = i & 15;
            float4 v4 = g[r * 16 + c];
            v4.x *= SCALEF; v4.y *= SCALEF; v4.z *= SCALEF; v4.w *= SCALEF;
            ((float4*)sQ)[r * 17 + c] = v4;
        }
    }

    const int qg = (l >> 4) * 4;     // q micro-tile base (0,4,8,12)
    const int kg = (l & 15) * 4;     // k micro-tile base within 64-subtile

    // ---- Phase A: scores = scale*QK^T + bias -> sS ----
    for (int s = 0; s < 4; ++s) {
        const int kbase = s * KT;
        __syncthreads();   // protect sKV reuse (also covers sQ staging at s=0)
        {
            const float4* g = (const float4*)(Kmat + hoff + (size_t)kbase * DD);
            for (int i = t; i < KT * 16; i += 256) {
                int r = i >> 4, c = i & 15;
                ((float4*)sKV)[r * 17 + c] = g[r * 16 + c];
            }
        }
        __syncthreads();
        const int ks = w * 64 + kg;  // k offset within this super-tile
        float acc[4][4];
        #pragma unroll
        for (int j = 0; j < 4; ++j)
            #pragma unroll
            for (int i = 0; i < 4; ++i) acc[j][i] = 0.0f;
        #pragma unroll 4
        for (int dv = 0; dv < 16; ++dv) {
            float4 kf[4];
            #pragma unroll
            for (int i = 0; i < 4; ++i)
                kf[i] = ((const float4*)sKV)[(ks + i) * 17 + dv];
            #pragma unroll
            for (int j = 0; j < 4; ++j) {
                float4 qf = ((const float4*)sQ)[(qg + j) * 17 + dv];
                #pragma unroll
                for (int i = 0; i < 4; ++i)
                    acc[j][i] += qf.x * kf[i].x + qf.y * kf[i].y +
                                 qf.z * kf[i].z + qf.w * kf[i].w;
            }
        }
        // add bias, write to sS
        const float* brow = bias + ((size_t)bh * LS + q0) * LS + kbase + ks;
        #pragma unroll
        for (int j = 0; j < 4; ++j) {
            float4 b4 = *(const float4*)(brow + (size_t)(qg + j) * LS);
            float4 r;
            r.x = acc[j][0] + b4.x; r.y = acc[j][1] + b4.y;
            r.z = acc[j][2] + b4.z; r.w = acc[j][3] + b4.w;
            *(float4*)&sS[qg + j][kbase + ks] = r;
        }
    }
    __syncthreads();

    // ---- Phase B: softmax + gate; wave w owns rows 4w..4w+3 ----
    const float* grow = gate + (size_t)bh * LS;
    for (int rr = 0; rr < 4; ++rr) {
        const int row = w * 4 + rr;
        float4 vals[4];
        float m = -1e30f;
        #pragma unroll
        for (int j = 0; j < 4; ++j) {
            vals[j] = *(const float4*)&sS[row][(l + 64 * j) * 4];
            m = fmaxf(m, fmaxf(fmaxf(vals[j].x, vals[j].y),
                               fmaxf(vals[j].z, vals[j].w)));
        }
        #pragma unroll
        for (int off = 32; off > 0; off >>= 1)
            m = fmaxf(m, __shfl_xor(m, off));
        float zsum = 0.0f;
        #pragma unroll
        for (int j = 0; j < 4; ++j) {
            vals[j].x = __expf(vals[j].x - m);
            vals[j].y = __expf(vals[j].y - m);
            vals[j].z = __expf(vals[j].z - m);
            vals[j].w = __expf(vals[j].w - m);
            zsum += vals[j].x + vals[j].y + vals[j].z + vals[j].w;
        }
        #pragma unroll
        for (int off = 32; off > 0; off >>= 1)
            zsum += __shfl_xor(zsum, off);
        const float inv = 1.0f / zsum;
        float* wrow = Wout + ((size_t)bh * LS + q0 + row) * LS;
        #pragma unroll
        for (int j = 0; j < 4; ++j) {
            const int cb = (l + 64 * j) * 4;
            float4 g4 = *(const float4*)(grow + cb);
            float4 w4;
            w4.x = vals[j].x * inv * g4.x;
            w4.y = vals[j].y * inv * g4.y;
            w4.z = vals[j].z * inv * g4.z;
            w4.w = vals[j].w * inv * g4.w;
            *(float4*)&sS[row][cb] = w4;       // for PV
            *(float4*)(wrow + cb) = w4;        // weights output
        }
    }
    __syncthreads();

    // ---- Phase C: O = W @ V ; wave w covers k in {s*256 + w*64 .. +63} ----
    const int dc = l & 15;          // float4 column of d
    float4 oacc[4];
    #pragma unroll
    for (int j = 0; j < 4; ++j) oacc[j] = make_float4(0.f, 0.f, 0.f, 0.f);
    for (int s = 0; s < 4; ++s) {
        const int kbase = s * KT;
        __syncthreads();
        {
            const float4* g = (const float4*)(V + hoff + (size_t)kbase * DD);
            for (int i = t; i < KT * 16; i += 256) {
                int r = i >> 4, c = i & 15;
                ((float4*)sKV)[r * 17 + c] = g[r * 16 + c];
            }
        }
        __syncthreads();
        const int ks = w * 64;
        for (int kk = 0; kk < 64; kk += 4) {
            float4 wf[4];
            #pragma unroll
            for (int j = 0; j < 4; ++j)
                wf[j] = *(const float4*)&sS[qg + j][kbase + ks + kk];
            float4 vf[4];
            #pragma unroll
            for (int i = 0; i < 4; ++i)
                vf[i] = ((const float4*)sKV)[(ks + kk + i) * 17 + dc];
            #pragma unroll
            for (int j = 0; j < 4; ++j) {
                const float* wj = (const float*)&wf[j];
                #pragma unroll
                for (int i = 0; i < 4; ++i) {
                    oacc[j].x += wj[i] * vf[i].x;
                    oacc[j].y += wj[i] * vf[i].y;
                    oacc[j].z += wj[i] * vf[i].z;
                    oacc[j].w += wj[i] * vf[i].w;
                }
            }
        }
    }
    __syncthreads();
    // cross-wave reduce of O partials through sKV region (16KB needed)
    float4* red = (float4*)sKV;   // [w][16 rows][16 f4cols]
    #pragma unroll
    for (int j = 0; j < 4; ++j)
        red[(w * 16 + qg + j) * 16 + dc] = oacc[j];
    __syncthreads();
    {
        const int r = t >> 4, c = t & 15;   // q row, f4 col
        float4 a0 = red[(0 * 16 + r) * 16 + c];
        float4 a1 = red[(1 * 16 + r) * 16 + c];
        float4 a2 = red[(2 * 16 + r) * 16 + c];
        float4 a3 = red[(3 * 16 + r) * 16 + c];
        float4 sum;
        sum.x = a0.x + a1.x + a2.x + a3.x;
        sum.y = a0.y + a1.y + a2.y + a3.y;
        sum.z = a0.z + a1.z + a2.z + a3.z;
        sum.w = a0.w + a1.w + a2.w + a3.w;
        const int b = bh >> 4, h = bh & 15;
        __hip_bfloat16* xp = tmp + ((size_t)(b * LS + q0 + r)) * DM + h * DD + c * 4;
        xp[0] = __float2bfloat16(sum.x);
        xp[1] = __float2bfloat16(sum.y);
        xp[2] = __float2bfloat16(sum.z);
        xp[3] = __float2bfloat16(sum.w);
    }
}

// ---------------------------------------------------------------------------
// Output projection: out[m][n] = b_out[n] + sum_k X[m][k] * W_out[n][k]
// X: bf16 [8192][1024] in ws; tile 128x128, K-step 64, 8x8 micro-tile.
// ---------------------------------------------------------------------------
#define PM 128
#define PN 128
__global__ __launch_bounds__(256) void proj_kernel(
    const __hip_bfloat16* __restrict__ X, const float* __restrict__ Wt,
    const float* __restrict__ bo, float* __restrict__ out)
{
    __shared__ __align__(16) float sX[PM][DD + 4];
    __shared__ __align__(16) float sW[PN][DD + 4];
    const int m0 = blockIdx.y * PM;
    const int n0 = blockIdx.x * PN;
    const int t  = threadIdx.x;
    const int mg = (t >> 4) * 8;
    const int ng = (t & 15) * 8;
    float acc[8][8];
    #pragma unroll
    for (int j = 0; j < 8; ++j)
        #pragma unroll
        for (int i = 0; i < 8; ++i) acc[j][i] = 0.0f;

    for (int kb = 0; kb < DM; kb += 64) {
        __syncthreads();
        // stage X (bf16 -> f32): 128 rows x 8 chunks of 8 bf16
        for (int i = t; i < PM * 8; i += 256) {
            int r = i >> 3, c = i & 7;
            union { float4 f; unsigned short u[8]; } uu;
            uu.f = *(const float4*)(X + (size_t)(m0 + r) * DM + kb + c * 8);
            float xs[8];
            #pragma unroll
            for (int z = 0; z < 8; ++z)
                xs[z] = __uint_as_float(((unsigned)uu.u[z]) << 16);
            float4 lo = {xs[0], xs[1], xs[2], xs[3]};
            float4 hi = {xs[4], xs[5], xs[6], xs[7]};
            ((float4*)sX)[r * 17 + c * 2]     = lo;
            ((float4*)sX)[r * 17 + c * 2 + 1] = hi;
        }
        // stage W: 128 rows x 16 f4
        for (int i = t; i < PN * 16; i += 256) {
            int r = i >> 4, c = i & 15;
            ((float4*)sW)[r * 17 + c] =
                *(const float4*)(Wt + (size_t)(n0 + r) * DM + kb + c * 4);
        }
        __syncthreads();
        #pragma unroll 4
        for (int dv = 0; dv < 16; ++dv) {
            float4 xf[8], wf[8];
            #pragma unroll
            for (int j = 0; j < 8; ++j)
                xf[j] = ((const float4*)sX)[(mg + j) * 17 + dv];
            #pragma unroll
            for (int i = 0; i < 8; ++i)
                wf[i] = ((const float4*)sW)[(ng + i) * 17 + dv];
            #pragma unroll
            for (int j = 0; j < 8; ++j)
                #pragma unroll
                for (int i = 0; i < 8; ++i)
                    acc[j][i] += xf[j].x * wf[i].x + xf[j].y * wf[i].y +
                                 xf[j].z * wf[i].z + xf[j].w * wf[i].w;
        }
    }
    // epilogue
    #pragma unroll
    for (int j = 0; j < 8; ++j) {
        float* orow = out + (size_t)(m0 + mg + j) * DM + n0 + ng;
        float4 r0, r1;
        r0.x = acc[j][0] + bo[n0 + ng + 0];
        r0.y = acc[j][1] + bo[n0 + ng + 1];
        r0.z = acc[j][2] + bo[n0 + ng + 2];
        r0.w = acc[j][3] + bo[n0 + ng + 3];
        r1.x = acc[j][4] + bo[n0 + ng + 4];
        r1.y = acc[j][5] + bo[n0 + ng + 5];
        r1.z = acc[j][6] + bo[n0 + ng + 6];
        r1.w = acc[j][7] + bo[n0 + ng + 7];
        *(float4*)orow       = r0;
        *(float4*)(orow + 4) = r1;
    }
}

// ---------------------------------------------------------------------------
extern "C" void kernel_launch(void* const* d_in, const int* in_sizes, int n_in,
                              void* d_out, int out_size, void* d_ws, size_t ws_size,
                              hipStream_t stream) {
    const float* q    = (const float*)d_in[0];
    const float* k    = (const float*)d_in[1];
    const float* v    = (const float*)d_in[2];
    const float* pt   = (const float*)d_in[3];
    const float* bias = (const float*)d_in[4];
    const float* W1   = (const float*)d_in[5];
    const float* b1   = (const float*)d_in[6];
    const float* W2   = (const float*)d_in[7];
    const float* b2   = (const float*)d_in[8];
    const float* Wo   = (const float*)d_in[9];
    const float* bo   = (const float*)d_in[10];

    float* out_graph   = (float*)d_out;                       // [8,1024,1024]
    float* out_weights = (float*)d_out + (size_t)NB * LS * DM; // [8,16,1024,1024]

    // ws layout: gate f32 [NBH*LS] (512KB) | tmp bf16 [NB*LS*DM] (16MB)
    float* gate = (float*)d_ws;
    __hip_bfloat16* tmp = (__hip_bfloat16*)((char*)d_ws + (size_t)NBH * LS * 4);

    gate_kernel<<<dim3(NBH * LS / 4), dim3(256), 0, stream>>>(
        pt, W1, b1, W2, b2, gate);
    attn_kernel<<<dim3(LS / QT, NBH), dim3(256), 0, stream>>>(
        q, k, v, bias, gate, out_weights, tmp);
    proj_kernel<<<dim3(DM / PN, NB * LS / PM), dim3(256), 0, stream>>>(
        tmp, Wo, bo, out_graph);
}